// Round 15
// baseline (175.451 us; speedup 1.0000x reference)
//
#include <hip/hip_runtime.h>
#include <math.h>

#define NPIX 16384
#define B_ 8

typedef __attribute__((ext_vector_type(4))) float f32x4;
typedef __attribute__((ext_vector_type(8))) short bf16x8;
typedef __attribute__((ext_vector_type(4))) unsigned int u32x4;

__device__ inline unsigned short f2bf(float f) {            // RNE fp32->bf16
  unsigned int u = __builtin_bit_cast(unsigned int, f);
  return (unsigned short)((u + 0x7fffu + ((u >> 16) & 1u)) >> 16);
}
__device__ inline float bf2f(unsigned short h) {
  unsigned int u = ((unsigned int)h) << 16;
  return __builtin_bit_cast(float, u);
}
__device__ inline unsigned int pack2(unsigned short a, unsigned short b) {
  return (unsigned int)a | ((unsigned int)b << 16);
}
__device__ inline f32x4 mfma16(bf16x8 a, bf16x8 b, f32x4 c) {
  return __builtin_amdgcn_mfma_f32_16x16x32_bf16(a, b, c, 0, 0, 0);
}
__device__ inline void unpack8(u32x4 u, float* f) {
#pragma unroll
  for (int i = 0; i < 4; ++i) {
    unsigned int w = u[i];
    f[2 * i]     = __builtin_bit_cast(float, w << 16);
    f[2 * i + 1] = __builtin_bit_cast(float, w & 0xffff0000u);
  }
}

// Layouts: qkv/qkvd are [b][row][192ch][128w]; ag is [b][row][256ch][128w].
// x, x1, y2, pc stay [b][ch][16384px].

// ---------- K0: merged weight prep (fold LN1 + bf16 converts) ----------
__global__ __launch_bounds__(256) void k0_prep(
    const float* __restrict__ wq, const float* __restrict__ lw,
    const float* __restrict__ lb, const float* __restrict__ pin,
    const float* __restrict__ pout, unsigned short* __restrict__ wq2,
    float* __restrict__ s1, float* __restrict__ s2,
    unsigned short* __restrict__ pinb, unsigned short* __restrict__ pob) {
  int bid = blockIdx.x, t = threadIdx.x;
  if (bid == 0) {
    if (t < 192) {
      int co = t;
      float a = 0.f, bsum = 0.f;
      for (int ci = 0; ci < 64; ++ci) {
        float w = wq[co * 64 + ci];
        unsigned short hb = f2bf(w * lw[ci]);
        wq2[co * 64 + ci] = hb;
        a += bf2f(hb);
        bsum = fmaf(w, lb[ci], bsum);
      }
      s1[co] = a;
      s2[co] = bsum;
    }
  } else if (bid <= 64) {
    int i = (bid - 1) * 256 + t;          // 16384 elements
    pinb[i] = f2bf(pin[i]);
  } else {
    int i = (bid - 65) * 256 + t;         // 8192 elements
    pob[i] = f2bf(pout[i]);
  }
}

// ---------- K1: LN1-folded qkv MFMA GEMM (64 -> 192), bf16 out ----------
__global__ __launch_bounds__(256) void k1_qkv(
    const float* __restrict__ x, const unsigned short* __restrict__ wq2,
    const float* __restrict__ s1, const float* __restrict__ s2,
    unsigned short* __restrict__ qkv) {
  __shared__ __align__(16) unsigned char lx[64 * 128];   // [pix][64ci] bf16, XOR-swizzled
  __shared__ float sumL[4][64], sqL[4][64], muL[64], rsL[64];
  __shared__ __align__(16) unsigned short epi[4][16][72];
  int t = threadIdx.x, blk = blockIdx.x;
  int b = blk >> 8, hw0 = (blk & 255) * 64;
  const float* xb = x + (size_t)b * 64 * NPIX + hw0;
  int p = t & 63, g8 = t >> 6;
  float psum = 0.f, psq = 0.f;
#pragma unroll
  for (int r = 0; r < 2; ++r) {
    int ci0 = g8 * 8 + r * 32;
    float v[8];
#pragma unroll
    for (int j = 0; j < 8; ++j) {
      v[j] = xb[(size_t)(ci0 + j) * NPIX + p];
      psum += v[j];
      psq = fmaf(v[j], v[j], psq);
    }
    u32x4 pk;
#pragma unroll
    for (int j = 0; j < 4; ++j) pk[j] = pack2(f2bf(v[2 * j]), f2bf(v[2 * j + 1]));
    unsigned int addr = ((unsigned)(p * 128 + ci0 * 2)) ^ ((p & 7) << 4);
    *(u32x4*)&lx[addr] = pk;
  }
  sumL[g8][p] = psum;
  sqL[g8][p] = psq;
  __syncthreads();
  if (t < 64) {
    float s = sumL[0][t] + sumL[1][t] + sumL[2][t] + sumL[3][t];
    float q = sqL[0][t] + sqL[1][t] + sqL[2][t] + sqL[3][t];
    float mu = s * (1.f / 64.f);
    float var = q * (1.f / 64.f) - mu * mu;
    muL[t] = mu;
    rsL[t] = rsqrtf(fmaxf(var, 0.f) + 1e-5f);
  }
  __syncthreads();
  int lane = t & 63, wv = t >> 6, l16 = lane & 15, g = lane >> 4;
  int co0 = wv * 48;
  bf16x8 A[3][2];
#pragma unroll
  for (int ct = 0; ct < 3; ++ct) {
    int co = co0 + ct * 16 + l16;
#pragma unroll
    for (int kh = 0; kh < 2; ++kh)
      A[ct][kh] = *(const bf16x8*)(wq2 + (size_t)co * 64 + kh * 32 + g * 8);
  }
  f32x4 acc[3][4];
#pragma unroll
  for (int ct = 0; ct < 3; ++ct)
#pragma unroll
    for (int nt = 0; nt < 4; ++nt) acc[ct][nt] = (f32x4)0.f;
#pragma unroll
  for (int nt = 0; nt < 4; ++nt) {
    int pp = nt * 16 + l16;
#pragma unroll
    for (int kh = 0; kh < 2; ++kh) {
      unsigned int addr = ((unsigned)(pp * 128 + (kh * 32 + g * 8) * 2)) ^ ((pp & 7) << 4);
      bf16x8 Bf = *(const bf16x8*)&lx[addr];
#pragma unroll
      for (int ct = 0; ct < 3; ++ct) acc[ct][nt] = mfma16(A[ct][kh], Bf, acc[ct][nt]);
    }
  }
  // epilogue -> qkv[b][row][co][w]
  int row1 = hw0 >> 7, wb1 = hw0 & 127;
  unsigned short* ob = qkv + ((size_t)(b * 128 + row1) * 192) * 128 + wb1;
#pragma unroll
  for (int ct = 0; ct < 3; ++ct) {
#pragma unroll
    for (int r = 0; r < 4; ++r) {
      int co = co0 + ct * 16 + g * 4 + r;
      float s1v = s1[co], s2v = s2[co];
#pragma unroll
      for (int nt = 0; nt < 4; ++nt) {
        int pl = nt * 16 + l16;
        float val = (acc[ct][nt][r] - muL[pl] * s1v) * rsL[pl] + s2v;
        epi[wv][g * 4 + r][pl] = f2bf(val);
      }
    }
#pragma unroll
    for (int i = 0; i < 2; ++i) {
      int chunk = i * 64 + lane, co_l = chunk >> 3, oct = chunk & 7;
      u32x4 v = *(const u32x4*)&epi[wv][co_l][oct * 8];
      *(u32x4*)(ob + (size_t)(co0 + ct * 16 + co_l) * 128 + oct * 8) = v;
    }
  }
}

// ---------- K2: depthwise 3x3 bf16, row-major layout ----------
__global__ __launch_bounds__(256) void k2_dw3x3(
    const unsigned short* __restrict__ in, const float* __restrict__ w9,
    unsigned short* __restrict__ out) {
  int blk0 = blockIdx.x;
  int blk = (blk0 & 7) * 1536 + (blk0 >> 3);  // XCD-chunked: 12288 = 8*1536
  int id = blk * 256 + threadIdx.x;           // ((b*128+row)*192+ch)*16 + oct
  int oct = id & 15;
  int cr = id >> 4;
  int ch = cr % 192;
  int br = cr / 192;                          // b*128 + row
  int row = br & 127;
  int w0 = oct * 8;
  const float* wp = w9 + ch * 9;
  float wgt[9];
#pragma unroll
  for (int j = 0; j < 9; ++j) wgt[j] = wp[j];
  float rowv[3][10];
#pragma unroll
  for (int dy = 0; dy < 3; ++dy) {
#pragma unroll
    for (int i = 0; i < 10; ++i) rowv[dy][i] = 0.f;
    int hh = row + dy - 1;
    if ((unsigned)hh < 128u) {
      const unsigned short* rp = in + ((size_t)(br + dy - 1) * 192 + ch) * 128 + w0;
      u32x4 m = *(const u32x4*)rp;
      unpack8(m, &rowv[dy][1]);
      if (w0 > 0) rowv[dy][0] = bf2f(rp[-1]);
      if (w0 < 120) rowv[dy][9] = bf2f(rp[8]);
    }
  }
  u32x4 res;
#pragma unroll
  for (int i = 0; i < 8; i += 2) {
    float a0 = 0.f, a1 = 0.f;
#pragma unroll
    for (int dy = 0; dy < 3; ++dy)
#pragma unroll
      for (int dx = 0; dx < 3; ++dx) {
        a0 = fmaf(wgt[dy * 3 + dx], rowv[dy][i + dx], a0);
        a1 = fmaf(wgt[dy * 3 + dx], rowv[dy][i + 1 + dx], a1);
      }
    res[i >> 1] = pack2(f2bf(a0), f2bf(a1));
  }
  *(u32x4*)(out + ((size_t)br * 192 + ch) * 128 + w0) = res;
}

// ---------- K3a: MFMA Gram tiles -> partial qq/kk/S per (b, 256px-chunk) ----------
__global__ __launch_bounds__(256) void k3a_mfma(
    const unsigned short* __restrict__ qkvd, float* __restrict__ parts) {
  __shared__ float red[4][640];
  int blk = blockIdx.x;            // 512 = 8b * 64chunks
  int b = blk >> 6, chunk = blk & 63;
  int t = threadIdx.x;
  int lane = t & 63, wv = t >> 6, l16 = lane & 15, g = lane >> 4;
  const unsigned short* bb = qkvd + (size_t)(b * 128) * 192 * 128;
  int n0 = chunk * 256 + wv * 64;
  f32x4 S[4], QQ[4], KK[4];
#pragma unroll
  for (int i = 0; i < 4; ++i) { S[i] = (f32x4)0.f; QQ[i] = (f32x4)0.f; KK[i] = (f32x4)0.f; }
#pragma unroll
  for (int ks = 0; ks < 2; ++ks) {
    int k0 = n0 + ks * 32 + g * 8;
    int r = k0 >> 7, w = k0 & 127;
    const unsigned short* rowb = bb + ((size_t)r * 192) * 128 + w;
    bf16x8 Q[4], K[4];
#pragma unroll
    for (int t4 = 0; t4 < 4; ++t4) {
      Q[t4] = *(const bf16x8*)(rowb + (size_t)(t4 * 16 + l16) * 128);
      K[t4] = *(const bf16x8*)(rowb + (size_t)(64 + t4 * 16 + l16) * 128);
    }
#pragma unroll
    for (int t4 = 0; t4 < 4; ++t4) {
      S[t4]  = mfma16(Q[t4], K[t4], S[t4]);
      QQ[t4] = mfma16(Q[t4], Q[t4], QQ[t4]);
      KK[t4] = mfma16(K[t4], K[t4], KK[t4]);
    }
  }
  int hi = l16 >> 3;
#pragma unroll
  for (int t4 = 0; t4 < 4; ++t4) {
#pragma unroll
    for (int r = 0; r < 4; ++r) {
      int m = g * 4 + r;
      if ((m >> 3) == hi) {
        int head = 2 * t4 + hi;
        red[wv][head * 80 + 16 + (m & 7) * 8 + (l16 & 7)] = S[t4][r];
      }
      if (m == l16) {
        int c = t4 * 16 + l16;
        red[wv][(c >> 3) * 80 + (c & 7)] = QQ[t4][r];
        red[wv][(c >> 3) * 80 + 8 + (c & 7)] = KK[t4][r];
      }
    }
  }
  __syncthreads();
  float* pb = parts + (size_t)blk * 640;
  for (int i = t; i < 640; i += 256)
    pb[i] = red[0][i] + red[1][i] + red[2][i] + red[3][i];
}

// ---------- K3bc: finalize attention + fold proj -> M_b[64][64] bf16 ----------
__global__ __launch_bounds__(256) void k3bc(
    const float* __restrict__ parts, const float* __restrict__ temp,
    const float* __restrict__ mix, const float* __restrict__ pw,
    unsigned short* __restrict__ M) {
  int b = blockIdx.x, t = threadIdx.x;
  __shared__ float s[8][80];
  __shared__ float att[8][64];
  for (int i = t; i < 640; i += 256) {
    const float* pbase = parts + (size_t)b * 64 * 640 + i;
    float v = 0.f;
    for (int c = 0; c < 64; ++c) v += pbase[c * 640];
    s[i / 80][i % 80] = v;
  }
  __syncthreads();
  float m0 = fmaxf(mix[0], mix[1]);
  float e0 = expf(mix[0] - m0), e1 = expf(mix[1] - m0);
  float w0 = e0 / (e0 + e1), w1 = e1 / (e0 + e1);
  for (int i = t; i < 512; i += 256) {
    int head = i >> 6, e = i & 63, c = e >> 3, d = e & 7;
    float tt = temp[head];
    float rq = 1.f / fmaxf(sqrtf(s[head][c]), 1e-12f);
    float sc[8];
    float mx = -1e30f;
#pragma unroll
    for (int d2 = 0; d2 < 8; ++d2) {
      float rk = 1.f / fmaxf(sqrtf(s[head][8 + d2]), 1e-12f);
      sc[d2] = s[head][16 + c * 8 + d2] * rq * rk;
      mx = fmaxf(mx, sc[d2] * tt);
    }
    float sum = 0.f;
#pragma unroll
    for (int d2 = 0; d2 < 8; ++d2) sum += expf(sc[d2] * tt - mx);
    float sm = expf(sc[d] * tt - mx) / sum;
    float r = fmaxf(sc[d], 0.f);
    r = r * r;
    att[head][e] = w0 * sm + w1 * r;
  }
  __syncthreads();
  for (int i = t; i < 4096; i += 256) {
    int co = i >> 6, ci = i & 63, head = ci >> 3, d = ci & 7;
    float a = 0.f;
#pragma unroll
    for (int cc = 0; cc < 8; ++cc)
      a = fmaf(pw[co * 64 + head * 8 + cc], att[head][cc * 8 + d], a);
    M[(size_t)b * 4096 + i] = f2bf(a);
  }
}

// ---------- K4: MFMA (proj∘attn)@v + residual + LN2, vectorized epilogue ----------
__global__ __launch_bounds__(256) void k4_av(
    const unsigned short* __restrict__ qkvd, const unsigned short* __restrict__ Mb,
    const float* __restrict__ x, const float* __restrict__ lw,
    const float* __restrict__ lb, unsigned short* __restrict__ x1,
    unsigned short* __restrict__ y2) {
  __shared__ __align__(16) unsigned char lv[64 * 128];
  __shared__ float sumL[4][64], sqL[4][64], muL[64], rsL[64];
  __shared__ __align__(16) unsigned short epi[4][16][72];
  int t = threadIdx.x, blk = blockIdx.x;
  int b = blk >> 8, hw0 = (blk & 255) * 64;
  int row4 = hw0 >> 7, wb4 = hw0 & 127;
  const unsigned short* vb = qkvd + ((size_t)(b * 128 + row4) * 192 + 128) * 128 + wb4;
  int p = t & 63, g8 = t >> 6;
#pragma unroll
  for (int r = 0; r < 2; ++r) {
    int ci0 = g8 * 8 + r * 32;
    unsigned short hh[8];
#pragma unroll
    for (int j = 0; j < 8; ++j) hh[j] = vb[(size_t)(ci0 + j) * 128 + p];
    u32x4 pk;
#pragma unroll
    for (int j = 0; j < 4; ++j) pk[j] = pack2(hh[2 * j], hh[2 * j + 1]);
    unsigned int addr = ((unsigned)(p * 128 + ci0 * 2)) ^ ((p & 7) << 4);
    *(u32x4*)&lv[addr] = pk;
  }
  __syncthreads();
  int lane = t & 63, wv = t >> 6, l16 = lane & 15, g = lane >> 4;
  bf16x8 A[2];
#pragma unroll
  for (int kh = 0; kh < 2; ++kh)
    A[kh] = *(const bf16x8*)(Mb + (size_t)b * 4096 + (size_t)(wv * 16 + l16) * 64 + kh * 32 + g * 8);
  f32x4 acc[4];
#pragma unroll
  for (int nt = 0; nt < 4; ++nt) acc[nt] = (f32x4)0.f;
#pragma unroll
  for (int nt = 0; nt < 4; ++nt) {
    int pp = nt * 16 + l16;
#pragma unroll
    for (int kh = 0; kh < 2; ++kh) {
      unsigned int addr = ((unsigned)(pp * 128 + (kh * 32 + g * 8) * 2)) ^ ((pp & 7) << 4);
      bf16x8 Bf = *(const bf16x8*)&lv[addr];
      acc[nt] = mfma16(A[kh], Bf, acc[nt]);
    }
  }
  const float* xb = x + (size_t)b * 64 * NPIX + hw0;
  unsigned short* x1b = x1 + (size_t)b * 64 * NPIX + hw0;
  float vals[4][4];
#pragma unroll
  for (int nt = 0; nt < 4; ++nt) {
    float ps = 0.f, pq = 0.f;
#pragma unroll
    for (int r = 0; r < 4; ++r) {
      int co = wv * 16 + g * 4 + r;
      size_t idx = (size_t)co * NPIX + nt * 16 + l16;
      float a = acc[nt][r] + xb[idx];
      vals[nt][r] = a;
      epi[wv][g * 4 + r][nt * 16 + l16] = f2bf(a);
      ps += a;
      pq = fmaf(a, a, pq);
    }
    ps += __shfl_xor(ps, 16); ps += __shfl_xor(ps, 32);
    pq += __shfl_xor(pq, 16); pq += __shfl_xor(pq, 32);
    if (g == 0) { sumL[wv][nt * 16 + l16] = ps; sqL[wv][nt * 16 + l16] = pq; }
  }
  // x1: per-wave LDS-transposed 16B stores (in-wave write->read)
#pragma unroll
  for (int i = 0; i < 2; ++i) {
    int chunk = i * 64 + lane, co_l = chunk >> 3, oct = chunk & 7;
    u32x4 v = *(const u32x4*)&epi[wv][co_l][oct * 8];
    *(u32x4*)(x1b + (size_t)(wv * 16 + co_l) * NPIX + oct * 8) = v;
  }
  __syncthreads();
  if (t < 64) {
    float s = sumL[0][t] + sumL[1][t] + sumL[2][t] + sumL[3][t];
    float q = sqL[0][t] + sqL[1][t] + sqL[2][t] + sqL[3][t];
    float mu = s * (1.f / 64.f);
    float var = q * (1.f / 64.f) - mu * mu;
    muL[t] = mu;
    rsL[t] = rsqrtf(fmaxf(var, 0.f) + 1e-5f);
  }
  __syncthreads();
  unsigned short* y2b = y2 + (size_t)b * 64 * NPIX + hw0;
#pragma unroll
  for (int nt = 0; nt < 4; ++nt)
#pragma unroll
    for (int r = 0; r < 4; ++r) {
      int co = wv * 16 + g * 4 + r;
      int pl = nt * 16 + l16;
      float yv = (vals[nt][r] - muL[pl]) * rsL[pl] * lw[co] + lb[co];
      epi[wv][g * 4 + r][pl] = f2bf(yv);
    }
#pragma unroll
  for (int i = 0; i < 2; ++i) {
    int chunk = i * 64 + lane, co_l = chunk >> 3, oct = chunk & 7;
    u32x4 v = *(const u32x4*)&epi[wv][co_l][oct * 8];
    *(u32x4*)(y2b + (size_t)(wv * 16 + co_l) * NPIX + oct * 8) = v;
  }
}

// ---------- K5: pconv 16->16 3x3 dense, LDS halo tile, scalar weights ----------
__global__ __launch_bounds__(256) void k5_pconv(
    const unsigned short* __restrict__ y2, const float* __restrict__ pcw,
    unsigned short* __restrict__ pc) {
  __shared__ unsigned short ly[16 * 120];   // [ci][10][12] (rows padded 10->12)
  int t = threadIdx.x, blk = blockIdx.x;
  int b = blk >> 8, tile = blk & 255;
  int ty = tile >> 4, tx = tile & 15;
  int h0 = ty * 8, w0 = tx * 8;
  const unsigned short* yb = y2 + (size_t)b * 64 * NPIX;
  for (int i = t; i < 1600; i += 256) {
    int ci = i / 100, r = i - ci * 100;
    int hy = r / 10, hx = r - hy * 10;
    int gh = h0 - 1 + hy, gw = w0 - 1 + hx;
    unsigned short v = 0;
    if ((unsigned)gh < 128u && (unsigned)gw < 128u) v = yb[(size_t)ci * NPIX + gh * 128 + gw];
    ly[ci * 120 + hy * 12 + hx] = v;
  }
  __syncthreads();
  int lp = t & 63;
  int py = lp >> 3, px = lp & 7;
  int cq = __builtin_amdgcn_readfirstlane(t >> 6);   // wave-uniform
  int co0 = cq * 4;
  float a0 = 0.f, a1 = 0.f, a2 = 0.f, a3 = 0.f;
  for (int ci = 0; ci < 16; ++ci) {
    float nb[9];
#pragma unroll
    for (int ky = 0; ky < 3; ++ky)
#pragma unroll
      for (int kx = 0; kx < 3; ++kx)
        nb[ky * 3 + kx] = bf2f(ly[ci * 120 + (py + ky) * 12 + px + kx]);
    const float* wp = pcw + (co0 * 16 + ci) * 9;
#pragma unroll
    for (int k = 0; k < 9; ++k) {
      a0 = fmaf(wp[k],       nb[k], a0);
      a1 = fmaf(wp[144 + k], nb[k], a1);
      a2 = fmaf(wp[288 + k], nb[k], a2);
      a3 = fmaf(wp[432 + k], nb[k], a3);
    }
  }
  size_t obase = (size_t)b * 16 * NPIX + (h0 + py) * 128 + w0 + px;
  pc[obase + (size_t)(co0 + 0) * NPIX] = f2bf(a0);
  pc[obase + (size_t)(co0 + 1) * NPIX] = f2bf(a1);
  pc[obase + (size_t)(co0 + 2) * NPIX] = f2bf(a2);
  pc[obase + (size_t)(co0 + 3) * NPIX] = f2bf(a3);
}

// ---------- K6: clean MFMA pin GEMM (K=64 -> 256), transposed epilogue ----------
__global__ __launch_bounds__(256) void k6_pin(
    const unsigned short* __restrict__ pc, const unsigned short* __restrict__ y2,
    const unsigned short* __restrict__ pinb, unsigned short* __restrict__ ag) {
  __shared__ __align__(16) unsigned char bt[64 * 128];      // [px][64ci] swizzled
  __shared__ __align__(16) unsigned short epi[4][16][72];   // [wave][co16][px64+pad]
  int t = threadIdx.x, blk = blockIdx.x;
  int b = blk >> 8, hw0 = (blk & 255) * 64;
  int px = t & 63, cb = t >> 6;
  {
    const unsigned short* base = (cb == 0) ? (pc + (size_t)b * 16 * NPIX)
                                           : (y2 + (size_t)b * 64 * NPIX);
#pragma unroll
    for (int j = 0; j < 16; j += 2) {
      int ch = cb * 16 + j;
      unsigned short v0 = base[(size_t)ch * NPIX + hw0 + px];
      unsigned short v1 = base[(size_t)(ch + 1) * NPIX + hw0 + px];
      unsigned int addr = ((unsigned)(px * 128 + ch * 2)) ^ ((px & 7) << 4);
      *(unsigned int*)&bt[addr] = pack2(v0, v1);
    }
  }
  __syncthreads();
  int lane = t & 63, wv = t >> 6, l16 = lane & 15, g = lane >> 4;
  bf16x8 A[4][2];
#pragma unroll
  for (int ct = 0; ct < 4; ++ct) {
    int co = wv * 64 + ct * 16 + l16;
#pragma unroll
    for (int kh = 0; kh < 2; ++kh)
      A[ct][kh] = *(const bf16x8*)(pinb + (size_t)co * 64 + kh * 32 + g * 8);
  }
  f32x4 acc[4][4];
#pragma unroll
  for (int ct = 0; ct < 4; ++ct)
#pragma unroll
    for (int nt = 0; nt < 4; ++nt) acc[ct][nt] = (f32x4)0.f;
#pragma unroll
  for (int nt = 0; nt < 4; ++nt) {
    int pp = nt * 16 + l16;
#pragma unroll
    for (int kh = 0; kh < 2; ++kh) {
      unsigned int addr = ((unsigned)(pp * 128 + (kh * 32 + g * 8) * 2)) ^ ((pp & 7) << 4);
      bf16x8 Bf = *(const bf16x8*)&bt[addr];
#pragma unroll
      for (int ct = 0; ct < 4; ++ct) acc[ct][nt] = mfma16(A[ct][kh], Bf, acc[ct][nt]);
    }
  }
  // epilogue -> ag[b][row][co][w]
  int row6 = hw0 >> 7, wb6 = hw0 & 127;
  unsigned short* ab = ag + ((size_t)(b * 128 + row6) * 256) * 128 + wb6;
#pragma unroll
  for (int ct = 0; ct < 4; ++ct) {
#pragma unroll
    for (int nt = 0; nt < 4; ++nt)
#pragma unroll
      for (int r = 0; r < 4; ++r)
        epi[wv][g * 4 + r][nt * 16 + l16] = f2bf(acc[ct][nt][r]);
#pragma unroll
    for (int i = 0; i < 2; ++i) {
      int chunk = i * 64 + lane, co_l = chunk >> 3, oct = chunk & 7;
      u32x4 v = *(const u32x4*)&epi[wv][co_l][oct * 8];
      int co = wv * 64 + ct * 16 + co_l;
      *(u32x4*)(ab + (size_t)co * 128 + oct * 8) = v;
    }
  }
}

// ---------- K7: fused dw3x3 + gelu*gate + MFMA pout, 512 threads ----------
// Same 64-px tile & fixed costs as the 40µs version, but 8 waves: phase-1 is
// ONE (ch-pair, px-octet) per thread (loads all issue up-front, round-10-level
// regs); phase-2 splits the 16 MFMA tiles 2-per-wave. Derived LDS banking for
// phase-1 writes: bank = (chp ^ ((i2^oct)<<2)) & 31 -> 2-way (free).
__global__ __launch_bounds__(512) void k7_fdfn(
    const unsigned short* __restrict__ ag, const float* __restrict__ dww,
    const unsigned short* __restrict__ pob, const unsigned short* __restrict__ x1,
    float* __restrict__ out) {
  __shared__ __align__(16) unsigned char bt[64 * 256];   // 16KB
  __shared__ float dwl[1152];
  int t = threadIdx.x;
  int blk0 = blockIdx.x;
  int blk = (blk0 & 7) * 256 + (blk0 >> 3);              // 2048 = 8*256, bijective
  int b = blk >> 8, rr = blk & 255;
  int row = rr >> 1, w0t = (rr & 1) * 64;
  for (int i = t; i < 1152; i += 512) dwl[i] = dww[i];

  // ---- phase 1a: loads (one ch-pair x one px-octet per thread) ----
  int chp = t >> 3, oct = t & 7;
  int ch0 = chp * 2;
  int w0 = w0t + oct * 8;
  bool hasL = (w0 > 0), hasR = (w0 < 120);
  u32x4 arow[2][3];
  u32x4 grow[2];
  unsigned short eL[2][3], eR[2][3];
#pragma unroll
  for (int cc = 0; cc < 2; ++cc) {
    int ch = ch0 + cc;
    grow[cc] = *(const u32x4*)(ag + ((size_t)(b * 128 + row) * 256 + 128 + ch) * 128 + w0);
#pragma unroll
    for (int dy = 0; dy < 3; ++dy) {
      int hh = row + dy - 1;
      bool v = (unsigned)hh < 128u;
      const unsigned short* rp = ag + ((size_t)(b * 128 + hh) * 256 + ch) * 128 + w0;
      arow[cc][dy] = v ? *(const u32x4*)rp : (u32x4)0u;
      eL[cc][dy] = (v && hasL) ? rp[-1] : (unsigned short)0;
      eR[cc][dy] = (v && hasR) ? rp[8] : (unsigned short)0;
    }
  }
  __syncthreads();   // dwl ready; loads above in flight

  // ---- phase 1b: compute h = gelu(dw(a)) * g, swizzled LDS write ----
  {
    unsigned short hv[2][8];
#pragma unroll
    for (int cc = 0; cc < 2; ++cc) {
      float rowa[3][10], gt[8];
#pragma unroll
      for (int dy = 0; dy < 3; ++dy) {
        rowa[dy][0] = bf2f(eL[cc][dy]);
        unpack8(arow[cc][dy], &rowa[dy][1]);
        rowa[dy][9] = bf2f(eR[cc][dy]);
      }
      unpack8(grow[cc], gt);
      float wgt[9];
#pragma unroll
      for (int j = 0; j < 9; ++j) wgt[j] = dwl[(ch0 + cc) * 9 + j];
#pragma unroll
      for (int i2 = 0; i2 < 8; ++i2) {
        float a = 0.f;
#pragma unroll
        for (int dy = 0; dy < 3; ++dy)
#pragma unroll
          for (int dx = 0; dx < 3; ++dx)
            a = fmaf(wgt[dy * 3 + dx], rowa[dy][i2 + dx], a);
        float gl = 0.5f * a * (1.f + erff(a * 0.70710678118654752f));
        hv[cc][i2] = f2bf(gl * gt[i2]);
      }
    }
#pragma unroll
    for (int i2 = 0; i2 < 8; ++i2) {
      int pxl = oct * 8 + i2;
      unsigned int f = (unsigned)(((pxl & 7) ^ (pxl >> 3)) << 4);
      unsigned int addr = (unsigned)(pxl * 256) + (((unsigned)(ch0 * 2)) ^ f);
      *(unsigned int*)&bt[addr] = pack2(hv[0][i2], hv[1][i2]);
    }
  }
  __syncthreads();
  // ---- phase 2: MFMA pout; wave wv -> co-tile (wv>>1), px-half (wv&1) ----
  int lane = t & 63, wv = t >> 6, l16 = lane & 15, g = lane >> 4;
  int cot = wv >> 1;
  int pxh = (wv & 1) * 2;
  bf16x8 A[4];
#pragma unroll
  for (int kh = 0; kh < 4; ++kh)
    A[kh] = *(const bf16x8*)(pob + (size_t)(cot * 16 + l16) * 128 + kh * 32 + g * 8);
  f32x4 acc[2];
#pragma unroll
  for (int j = 0; j < 2; ++j) acc[j] = (f32x4)0.f;
#pragma unroll
  for (int j = 0; j < 2; ++j) {
    int pp = (pxh + j) * 16 + l16;
    unsigned int f = (unsigned)(((pp & 7) ^ (pp >> 3)) << 4);
#pragma unroll
    for (int kh = 0; kh < 4; ++kh) {
      unsigned int addr = (unsigned)(pp * 256) + (((unsigned)((kh * 32 + g * 8) * 2)) ^ f);
      bf16x8 Bf = *(const bf16x8*)&bt[addr];
      acc[j] = mfma16(A[kh], Bf, acc[j]);
    }
  }
  __syncthreads();
  // ---- epilogue: per-wave f32 [16co][32px] in bt; 16B stores + residual ----
  float* ebuf = (float*)&bt[wv * 2048];
#pragma unroll
  for (int j = 0; j < 2; ++j)
#pragma unroll
    for (int r = 0; r < 4; ++r)
      ebuf[(g * 4 + r) * 32 + j * 16 + l16] = acc[j][r];
  int pxb = (wv & 1) * 32;
  const unsigned short* x1b = x1 + (size_t)b * 64 * NPIX + row * 128 + w0t + pxb;
  float* ob = out + (size_t)b * 64 * NPIX + row * 128 + w0t + pxb;
#pragma unroll
  for (int i = 0; i < 2; ++i) {
    int chunk = i * 64 + lane;          // 0..127
    int co_l = chunk >> 3, q4 = (chunk & 7) * 4;
    f32x4 v = *(const f32x4*)&ebuf[co_l * 32 + q4];
    int co = cot * 16 + co_l;
    uint2 xv = *(const uint2*)(x1b + (size_t)co * NPIX + q4);
    f32x4 o;
    o[0] = v[0] + bf2f((unsigned short)(xv.x & 0xffffu));
    o[1] = v[1] + bf2f((unsigned short)(xv.x >> 16));
    o[2] = v[2] + bf2f((unsigned short)(xv.y & 0xffffu));
    o[3] = v[3] + bf2f((unsigned short)(xv.y >> 16));
    *(f32x4*)(ob + (size_t)co * NPIX + q4) = o;
  }
}

// ---------- launch ----------
extern "C" void kernel_launch(void* const* d_in, const int* in_sizes, int n_in,
                              void* d_out, int out_size, void* d_ws, size_t ws_size,
                              hipStream_t stream) {
  const float* x       = (const float*)d_in[0];
  const float* ln1_w   = (const float*)d_in[1];
  const float* ln1_b   = (const float*)d_in[2];
  const float* qkv_w   = (const float*)d_in[3];
  const float* qkv_dww = (const float*)d_in[4];
  const float* temp    = (const float*)d_in[5];
  const float* mix     = (const float*)d_in[6];
  const float* proj_w  = (const float*)d_in[7];
  const float* ln2_w   = (const float*)d_in[8];
  const float* ln2_b   = (const float*)d_in[9];
  const float* pconv_w = (const float*)d_in[10];
  const float* pin_w   = (const float*)d_in[11];
  const float* dw_w    = (const float*)d_in[12];
  const float* pout_w  = (const float*)d_in[13];
  float* out = (float*)d_out;

  // Workspace (byte offsets):
  //   qkv  [0, 50331648)           k1->k2 (bf16, row-major)
  //   qkvd [50331648, 100663296)   k2->k4 (bf16, row-major)
  //   x1   [100663296, 117440512)  k4->k7 (bf16)
  //   weights @117440512
  //   parts @0, M @2MB, y2 @4MB, pc @20.97MB -- in dead qkv head
  //   ag   [33554432, 100663296)   k6->k7 (row-major; dead qkv tail + dead qkvd)
  if (ws_size < (size_t)117515776) return;
  char* w8 = (char*)d_ws;
  unsigned short* qkv  = (unsigned short*)(w8 + 0);
  unsigned short* qkvd = (unsigned short*)(w8 + 50331648);
  unsigned short* x1   = (unsigned short*)(w8 + 100663296);
  unsigned short* wq2  = (unsigned short*)(w8 + 117440512);
  float*          s1   = (float*)(w8 + 117465088);
  float*          s2   = (float*)(w8 + 117465856);
  unsigned short* pinb = (unsigned short*)(w8 + 117466624);
  unsigned short* pob  = (unsigned short*)(w8 + 117499392);
  float*          parts= (float*)(w8 + 0);
  unsigned short* M    = (unsigned short*)(w8 + 2097152);
  unsigned short* y2   = (unsigned short*)(w8 + 4194304);
  unsigned short* pc   = (unsigned short*)(w8 + 20971520);
  unsigned short* ag   = (unsigned short*)(w8 + 33554432);

  k0_prep<<<97, 256, 0, stream>>>(qkv_w, ln1_w, ln1_b, pin_w, pout_w, wq2, s1, s2, pinb, pob);
  k1_qkv<<<2048, 256, 0, stream>>>(x, wq2, s1, s2, qkv);
  k2_dw3x3<<<12288, 256, 0, stream>>>(qkv, qkv_dww, qkvd);
  k3a_mfma<<<512, 256, 0, stream>>>(qkvd, parts);
  k3bc<<<8, 256, 0, stream>>>(parts, temp, mix, proj_w, M);
  k4_av<<<2048, 256, 0, stream>>>(qkvd, M, x, ln2_w, ln2_b, x1, y2);
  k5_pconv<<<2048, 256, 0, stream>>>(y2, pconv_w, pc);
  k6_pin<<<2048, 256, 0, stream>>>(pc, y2, pinb, ag);
  k7_fdfn<<<2048, 512, 0, stream>>>(ag, dw_w, pob, x1, out);
}

// Round 16
// 165.430 us; speedup vs baseline: 1.0606x; 1.0606x over previous
//
#include <hip/hip_runtime.h>
#include <math.h>

#define NPIX 16384
#define B_ 8

typedef __attribute__((ext_vector_type(4))) float f32x4;
typedef __attribute__((ext_vector_type(8))) short bf16x8;
typedef __attribute__((ext_vector_type(4))) unsigned int u32x4;

__device__ inline unsigned short f2bf(float f) {            // RNE fp32->bf16
  unsigned int u = __builtin_bit_cast(unsigned int, f);
  return (unsigned short)((u + 0x7fffu + ((u >> 16) & 1u)) >> 16);
}
__device__ inline float bf2f(unsigned short h) {
  unsigned int u = ((unsigned int)h) << 16;
  return __builtin_bit_cast(float, u);
}
__device__ inline unsigned int pack2(unsigned short a, unsigned short b) {
  return (unsigned int)a | ((unsigned int)b << 16);
}
__device__ inline f32x4 mfma16(bf16x8 a, bf16x8 b, f32x4 c) {
  return __builtin_amdgcn_mfma_f32_16x16x32_bf16(a, b, c, 0, 0, 0);
}
__device__ inline void unpack8(u32x4 u, float* f) {
#pragma unroll
  for (int i = 0; i < 4; ++i) {
    unsigned int w = u[i];
    f[2 * i]     = __builtin_bit_cast(float, w << 16);
    f[2 * i + 1] = __builtin_bit_cast(float, w & 0xffff0000u);
  }
}

// Layouts: qkv/qkvd are [b][row][192ch][128w]; ag is [b][row][256ch][128w].
// x, x1, y2, pc stay [b][ch][16384px].

// ---------- K0: merged weight prep (fold LN1 + bf16 converts) ----------
__global__ __launch_bounds__(256) void k0_prep(
    const float* __restrict__ wq, const float* __restrict__ lw,
    const float* __restrict__ lb, const float* __restrict__ pin,
    const float* __restrict__ pout, unsigned short* __restrict__ wq2,
    float* __restrict__ s1, float* __restrict__ s2,
    unsigned short* __restrict__ pinb, unsigned short* __restrict__ pob) {
  int bid = blockIdx.x, t = threadIdx.x;
  if (bid == 0) {
    if (t < 192) {
      int co = t;
      float a = 0.f, bsum = 0.f;
      for (int ci = 0; ci < 64; ++ci) {
        float w = wq[co * 64 + ci];
        unsigned short hb = f2bf(w * lw[ci]);
        wq2[co * 64 + ci] = hb;
        a += bf2f(hb);
        bsum = fmaf(w, lb[ci], bsum);
      }
      s1[co] = a;
      s2[co] = bsum;
    }
  } else if (bid <= 64) {
    int i = (bid - 1) * 256 + t;          // 16384 elements
    pinb[i] = f2bf(pin[i]);
  } else {
    int i = (bid - 65) * 256 + t;         // 8192 elements
    pob[i] = f2bf(pout[i]);
  }
}

// ---------- K1: LN1-folded qkv MFMA GEMM (64 -> 192), bf16 out ----------
__global__ __launch_bounds__(256) void k1_qkv(
    const float* __restrict__ x, const unsigned short* __restrict__ wq2,
    const float* __restrict__ s1, const float* __restrict__ s2,
    unsigned short* __restrict__ qkv) {
  __shared__ __align__(16) unsigned char lx[64 * 128];   // [pix][64ci] bf16, XOR-swizzled
  __shared__ float sumL[4][64], sqL[4][64], muL[64], rsL[64];
  __shared__ __align__(16) unsigned short epi[4][16][72];
  int t = threadIdx.x, blk = blockIdx.x;
  int b = blk >> 8, hw0 = (blk & 255) * 64;
  const float* xb = x + (size_t)b * 64 * NPIX + hw0;
  int p = t & 63, g8 = t >> 6;
  float psum = 0.f, psq = 0.f;
#pragma unroll
  for (int r = 0; r < 2; ++r) {
    int ci0 = g8 * 8 + r * 32;
    float v[8];
#pragma unroll
    for (int j = 0; j < 8; ++j) {
      v[j] = xb[(size_t)(ci0 + j) * NPIX + p];
      psum += v[j];
      psq = fmaf(v[j], v[j], psq);
    }
    u32x4 pk;
#pragma unroll
    for (int j = 0; j < 4; ++j) pk[j] = pack2(f2bf(v[2 * j]), f2bf(v[2 * j + 1]));
    unsigned int addr = ((unsigned)(p * 128 + ci0 * 2)) ^ ((p & 7) << 4);
    *(u32x4*)&lx[addr] = pk;
  }
  sumL[g8][p] = psum;
  sqL[g8][p] = psq;
  __syncthreads();
  if (t < 64) {
    float s = sumL[0][t] + sumL[1][t] + sumL[2][t] + sumL[3][t];
    float q = sqL[0][t] + sqL[1][t] + sqL[2][t] + sqL[3][t];
    float mu = s * (1.f / 64.f);
    float var = q * (1.f / 64.f) - mu * mu;
    muL[t] = mu;
    rsL[t] = rsqrtf(fmaxf(var, 0.f) + 1e-5f);
  }
  __syncthreads();
  int lane = t & 63, wv = t >> 6, l16 = lane & 15, g = lane >> 4;
  int co0 = wv * 48;
  bf16x8 A[3][2];
#pragma unroll
  for (int ct = 0; ct < 3; ++ct) {
    int co = co0 + ct * 16 + l16;
#pragma unroll
    for (int kh = 0; kh < 2; ++kh)
      A[ct][kh] = *(const bf16x8*)(wq2 + (size_t)co * 64 + kh * 32 + g * 8);
  }
  f32x4 acc[3][4];
#pragma unroll
  for (int ct = 0; ct < 3; ++ct)
#pragma unroll
    for (int nt = 0; nt < 4; ++nt) acc[ct][nt] = (f32x4)0.f;
#pragma unroll
  for (int nt = 0; nt < 4; ++nt) {
    int pp = nt * 16 + l16;
#pragma unroll
    for (int kh = 0; kh < 2; ++kh) {
      unsigned int addr = ((unsigned)(pp * 128 + (kh * 32 + g * 8) * 2)) ^ ((pp & 7) << 4);
      bf16x8 Bf = *(const bf16x8*)&lx[addr];
#pragma unroll
      for (int ct = 0; ct < 3; ++ct) acc[ct][nt] = mfma16(A[ct][kh], Bf, acc[ct][nt]);
    }
  }
  // epilogue -> qkv[b][row][co][w]
  int row1 = hw0 >> 7, wb1 = hw0 & 127;
  unsigned short* ob = qkv + ((size_t)(b * 128 + row1) * 192) * 128 + wb1;
#pragma unroll
  for (int ct = 0; ct < 3; ++ct) {
#pragma unroll
    for (int r = 0; r < 4; ++r) {
      int co = co0 + ct * 16 + g * 4 + r;
      float s1v = s1[co], s2v = s2[co];
#pragma unroll
      for (int nt = 0; nt < 4; ++nt) {
        int pl = nt * 16 + l16;
        float val = (acc[ct][nt][r] - muL[pl] * s1v) * rsL[pl] + s2v;
        epi[wv][g * 4 + r][pl] = f2bf(val);
      }
    }
#pragma unroll
    for (int i = 0; i < 2; ++i) {
      int chunk = i * 64 + lane, co_l = chunk >> 3, oct = chunk & 7;
      u32x4 v = *(const u32x4*)&epi[wv][co_l][oct * 8];
      *(u32x4*)(ob + (size_t)(co0 + ct * 16 + co_l) * 128 + oct * 8) = v;
    }
  }
}

// ---------- K2: depthwise 3x3 bf16, row-major, 2 output rows/thread ----------
// Loads 4 rows to produce 2 (vs 3-for-1): 33% fewer halo loads.
__global__ __launch_bounds__(256) void k2_dw3x3(
    const unsigned short* __restrict__ in, const float* __restrict__ w9,
    unsigned short* __restrict__ out) {
  int blk0 = blockIdx.x;
  int blk = (blk0 & 7) * 768 + (blk0 >> 3);   // XCD-chunked: 6144 = 8*768
  int id = blk * 256 + threadIdx.x;           // ((b*64+rp)*192+ch)*16 + oct
  int oct = id & 15;
  int cr = id >> 4;
  int ch = cr % 192;
  int brp = cr / 192;                         // b*64 + rowpair
  int b = brp >> 6;
  int row0 = (brp & 63) * 2;
  int w0 = oct * 8;
  const float* wp = w9 + ch * 9;
  float wgt[9];
#pragma unroll
  for (int j = 0; j < 9; ++j) wgt[j] = wp[j];
  float rowv[4][10];
#pragma unroll
  for (int dy = 0; dy < 4; ++dy) {
#pragma unroll
    for (int i = 0; i < 10; ++i) rowv[dy][i] = 0.f;
    int hh = row0 + dy - 1;
    if ((unsigned)hh < 128u) {
      const unsigned short* rp = in + ((size_t)(b * 128 + hh) * 192 + ch) * 128 + w0;
      u32x4 m = *(const u32x4*)rp;
      unpack8(m, &rowv[dy][1]);
      if (w0 > 0) rowv[dy][0] = bf2f(rp[-1]);
      if (w0 < 120) rowv[dy][9] = bf2f(rp[8]);
    }
  }
#pragma unroll
  for (int ro = 0; ro < 2; ++ro) {
    u32x4 res;
#pragma unroll
    for (int i = 0; i < 8; i += 2) {
      float a0 = 0.f, a1 = 0.f;
#pragma unroll
      for (int dy = 0; dy < 3; ++dy)
#pragma unroll
        for (int dx = 0; dx < 3; ++dx) {
          a0 = fmaf(wgt[dy * 3 + dx], rowv[ro + dy][i + dx], a0);
          a1 = fmaf(wgt[dy * 3 + dx], rowv[ro + dy][i + 1 + dx], a1);
        }
      res[i >> 1] = pack2(f2bf(a0), f2bf(a1));
    }
    *(u32x4*)(out + ((size_t)(b * 128 + row0 + ro) * 192 + ch) * 128 + w0) = res;
  }
}

// ---------- K3a: MFMA Gram tiles -> partial qq/kk/S per (b, 256px-chunk) ----------
__global__ __launch_bounds__(256) void k3a_mfma(
    const unsigned short* __restrict__ qkvd, float* __restrict__ parts) {
  __shared__ float red[4][640];
  int blk = blockIdx.x;            // 512 = 8b * 64chunks
  int b = blk >> 6, chunk = blk & 63;
  int t = threadIdx.x;
  int lane = t & 63, wv = t >> 6, l16 = lane & 15, g = lane >> 4;
  const unsigned short* bb = qkvd + (size_t)(b * 128) * 192 * 128;
  int n0 = chunk * 256 + wv * 64;
  f32x4 S[4], QQ[4], KK[4];
#pragma unroll
  for (int i = 0; i < 4; ++i) { S[i] = (f32x4)0.f; QQ[i] = (f32x4)0.f; KK[i] = (f32x4)0.f; }
#pragma unroll
  for (int ks = 0; ks < 2; ++ks) {
    int k0 = n0 + ks * 32 + g * 8;
    int r = k0 >> 7, w = k0 & 127;
    const unsigned short* rowb = bb + ((size_t)r * 192) * 128 + w;
    bf16x8 Q[4], K[4];
#pragma unroll
    for (int t4 = 0; t4 < 4; ++t4) {
      Q[t4] = *(const bf16x8*)(rowb + (size_t)(t4 * 16 + l16) * 128);
      K[t4] = *(const bf16x8*)(rowb + (size_t)(64 + t4 * 16 + l16) * 128);
    }
#pragma unroll
    for (int t4 = 0; t4 < 4; ++t4) {
      S[t4]  = mfma16(Q[t4], K[t4], S[t4]);
      QQ[t4] = mfma16(Q[t4], Q[t4], QQ[t4]);
      KK[t4] = mfma16(K[t4], K[t4], KK[t4]);
    }
  }
  int hi = l16 >> 3;
#pragma unroll
  for (int t4 = 0; t4 < 4; ++t4) {
#pragma unroll
    for (int r = 0; r < 4; ++r) {
      int m = g * 4 + r;
      if ((m >> 3) == hi) {
        int head = 2 * t4 + hi;
        red[wv][head * 80 + 16 + (m & 7) * 8 + (l16 & 7)] = S[t4][r];
      }
      if (m == l16) {
        int c = t4 * 16 + l16;
        red[wv][(c >> 3) * 80 + (c & 7)] = QQ[t4][r];
        red[wv][(c >> 3) * 80 + 8 + (c & 7)] = KK[t4][r];
      }
    }
  }
  __syncthreads();
  float* pb = parts + (size_t)blk * 640;
  for (int i = t; i < 640; i += 256)
    pb[i] = red[0][i] + red[1][i] + red[2][i] + red[3][i];
}

// ---------- K3bc: finalize attention + fold proj -> M_b[64][64] bf16 ----------
__global__ __launch_bounds__(256) void k3bc(
    const float* __restrict__ parts, const float* __restrict__ temp,
    const float* __restrict__ mix, const float* __restrict__ pw,
    unsigned short* __restrict__ M) {
  int b = blockIdx.x, t = threadIdx.x;
  __shared__ float s[8][80];
  __shared__ float att[8][64];
  for (int i = t; i < 640; i += 256) {
    const float* pbase = parts + (size_t)b * 64 * 640 + i;
    float v = 0.f;
    for (int c = 0; c < 64; ++c) v += pbase[c * 640];
    s[i / 80][i % 80] = v;
  }
  __syncthreads();
  float m0 = fmaxf(mix[0], mix[1]);
  float e0 = expf(mix[0] - m0), e1 = expf(mix[1] - m0);
  float w0 = e0 / (e0 + e1), w1 = e1 / (e0 + e1);
  for (int i = t; i < 512; i += 256) {
    int head = i >> 6, e = i & 63, c = e >> 3, d = e & 7;
    float tt = temp[head];
    float rq = 1.f / fmaxf(sqrtf(s[head][c]), 1e-12f);
    float sc[8];
    float mx = -1e30f;
#pragma unroll
    for (int d2 = 0; d2 < 8; ++d2) {
      float rk = 1.f / fmaxf(sqrtf(s[head][8 + d2]), 1e-12f);
      sc[d2] = s[head][16 + c * 8 + d2] * rq * rk;
      mx = fmaxf(mx, sc[d2] * tt);
    }
    float sum = 0.f;
#pragma unroll
    for (int d2 = 0; d2 < 8; ++d2) sum += expf(sc[d2] * tt - mx);
    float sm = expf(sc[d] * tt - mx) / sum;
    float r = fmaxf(sc[d], 0.f);
    r = r * r;
    att[head][e] = w0 * sm + w1 * r;
  }
  __syncthreads();
  for (int i = t; i < 4096; i += 256) {
    int co = i >> 6, ci = i & 63, head = ci >> 3, d = ci & 7;
    float a = 0.f;
#pragma unroll
    for (int cc = 0; cc < 8; ++cc)
      a = fmaf(pw[co * 64 + head * 8 + cc], att[head][cc * 8 + d], a);
    M[(size_t)b * 4096 + i] = f2bf(a);
  }
}

// ---------- K4: MFMA (proj∘attn)@v + residual + LN2, vectorized epilogue ----------
__global__ __launch_bounds__(256) void k4_av(
    const unsigned short* __restrict__ qkvd, const unsigned short* __restrict__ Mb,
    const float* __restrict__ x, const float* __restrict__ lw,
    const float* __restrict__ lb, unsigned short* __restrict__ x1,
    unsigned short* __restrict__ y2) {
  __shared__ __align__(16) unsigned char lv[64 * 128];
  __shared__ float sumL[4][64], sqL[4][64], muL[64], rsL[64];
  __shared__ __align__(16) unsigned short epi[4][16][72];
  int t = threadIdx.x, blk = blockIdx.x;
  int b = blk >> 8, hw0 = (blk & 255) * 64;
  int row4 = hw0 >> 7, wb4 = hw0 & 127;
  const unsigned short* vb = qkvd + ((size_t)(b * 128 + row4) * 192 + 128) * 128 + wb4;
  int p = t & 63, g8 = t >> 6;
#pragma unroll
  for (int r = 0; r < 2; ++r) {
    int ci0 = g8 * 8 + r * 32;
    unsigned short hh[8];
#pragma unroll
    for (int j = 0; j < 8; ++j) hh[j] = vb[(size_t)(ci0 + j) * 128 + p];
    u32x4 pk;
#pragma unroll
    for (int j = 0; j < 4; ++j) pk[j] = pack2(hh[2 * j], hh[2 * j + 1]);
    unsigned int addr = ((unsigned)(p * 128 + ci0 * 2)) ^ ((p & 7) << 4);
    *(u32x4*)&lv[addr] = pk;
  }
  __syncthreads();
  int lane = t & 63, wv = t >> 6, l16 = lane & 15, g = lane >> 4;
  bf16x8 A[2];
#pragma unroll
  for (int kh = 0; kh < 2; ++kh)
    A[kh] = *(const bf16x8*)(Mb + (size_t)b * 4096 + (size_t)(wv * 16 + l16) * 64 + kh * 32 + g * 8);
  f32x4 acc[4];
#pragma unroll
  for (int nt = 0; nt < 4; ++nt) acc[nt] = (f32x4)0.f;
#pragma unroll
  for (int nt = 0; nt < 4; ++nt) {
    int pp = nt * 16 + l16;
#pragma unroll
    for (int kh = 0; kh < 2; ++kh) {
      unsigned int addr = ((unsigned)(pp * 128 + (kh * 32 + g * 8) * 2)) ^ ((pp & 7) << 4);
      bf16x8 Bf = *(const bf16x8*)&lv[addr];
      acc[nt] = mfma16(A[kh], Bf, acc[nt]);
    }
  }
  const float* xb = x + (size_t)b * 64 * NPIX + hw0;
  unsigned short* x1b = x1 + (size_t)b * 64 * NPIX + hw0;
  float vals[4][4];
#pragma unroll
  for (int nt = 0; nt < 4; ++nt) {
    float ps = 0.f, pq = 0.f;
#pragma unroll
    for (int r = 0; r < 4; ++r) {
      int co = wv * 16 + g * 4 + r;
      size_t idx = (size_t)co * NPIX + nt * 16 + l16;
      float a = acc[nt][r] + xb[idx];
      vals[nt][r] = a;
      epi[wv][g * 4 + r][nt * 16 + l16] = f2bf(a);
      ps += a;
      pq = fmaf(a, a, pq);
    }
    ps += __shfl_xor(ps, 16); ps += __shfl_xor(ps, 32);
    pq += __shfl_xor(pq, 16); pq += __shfl_xor(pq, 32);
    if (g == 0) { sumL[wv][nt * 16 + l16] = ps; sqL[wv][nt * 16 + l16] = pq; }
  }
  // x1: per-wave LDS-transposed 16B stores (in-wave write->read)
#pragma unroll
  for (int i = 0; i < 2; ++i) {
    int chunk = i * 64 + lane, co_l = chunk >> 3, oct = chunk & 7;
    u32x4 v = *(const u32x4*)&epi[wv][co_l][oct * 8];
    *(u32x4*)(x1b + (size_t)(wv * 16 + co_l) * NPIX + oct * 8) = v;
  }
  __syncthreads();
  if (t < 64) {
    float s = sumL[0][t] + sumL[1][t] + sumL[2][t] + sumL[3][t];
    float q = sqL[0][t] + sqL[1][t] + sqL[2][t] + sqL[3][t];
    float mu = s * (1.f / 64.f);
    float var = q * (1.f / 64.f) - mu * mu;
    muL[t] = mu;
    rsL[t] = rsqrtf(fmaxf(var, 0.f) + 1e-5f);
  }
  __syncthreads();
  unsigned short* y2b = y2 + (size_t)b * 64 * NPIX + hw0;
#pragma unroll
  for (int nt = 0; nt < 4; ++nt)
#pragma unroll
    for (int r = 0; r < 4; ++r) {
      int co = wv * 16 + g * 4 + r;
      int pl = nt * 16 + l16;
      float yv = (vals[nt][r] - muL[pl]) * rsL[pl] * lw[co] + lb[co];
      epi[wv][g * 4 + r][pl] = f2bf(yv);
    }
#pragma unroll
  for (int i = 0; i < 2; ++i) {
    int chunk = i * 64 + lane, co_l = chunk >> 3, oct = chunk & 7;
    u32x4 v = *(const u32x4*)&epi[wv][co_l][oct * 8];
    *(u32x4*)(y2b + (size_t)(wv * 16 + co_l) * NPIX + oct * 8) = v;
  }
}

// ---------- K5: pconv 16->16 3x3 dense, LDS halo tile, scalar weights ----------
__global__ __launch_bounds__(256) void k5_pconv(
    const unsigned short* __restrict__ y2, const float* __restrict__ pcw,
    unsigned short* __restrict__ pc) {
  __shared__ unsigned short ly[16 * 120];   // [ci][10][12] (rows padded 10->12)
  int t = threadIdx.x, blk = blockIdx.x;
  int b = blk >> 8, tile = blk & 255;
  int ty = tile >> 4, tx = tile & 15;
  int h0 = ty * 8, w0 = tx * 8;
  const unsigned short* yb = y2 + (size_t)b * 64 * NPIX;
  for (int i = t; i < 1600; i += 256) {
    int ci = i / 100, r = i - ci * 100;
    int hy = r / 10, hx = r - hy * 10;
    int gh = h0 - 1 + hy, gw = w0 - 1 + hx;
    unsigned short v = 0;
    if ((unsigned)gh < 128u && (unsigned)gw < 128u) v = yb[(size_t)ci * NPIX + gh * 128 + gw];
    ly[ci * 120 + hy * 12 + hx] = v;
  }
  __syncthreads();
  int lp = t & 63;
  int py = lp >> 3, px = lp & 7;
  int cq = __builtin_amdgcn_readfirstlane(t >> 6);   // wave-uniform
  int co0 = cq * 4;
  float a0 = 0.f, a1 = 0.f, a2 = 0.f, a3 = 0.f;
  for (int ci = 0; ci < 16; ++ci) {
    float nb[9];
#pragma unroll
    for (int ky = 0; ky < 3; ++ky)
#pragma unroll
      for (int kx = 0; kx < 3; ++kx)
        nb[ky * 3 + kx] = bf2f(ly[ci * 120 + (py + ky) * 12 + px + kx]);
    const float* wp = pcw + (co0 * 16 + ci) * 9;
#pragma unroll
    for (int k = 0; k < 9; ++k) {
      a0 = fmaf(wp[k],       nb[k], a0);
      a1 = fmaf(wp[144 + k], nb[k], a1);
      a2 = fmaf(wp[288 + k], nb[k], a2);
      a3 = fmaf(wp[432 + k], nb[k], a3);
    }
  }
  size_t obase = (size_t)b * 16 * NPIX + (h0 + py) * 128 + w0 + px;
  pc[obase + (size_t)(co0 + 0) * NPIX] = f2bf(a0);
  pc[obase + (size_t)(co0 + 1) * NPIX] = f2bf(a1);
  pc[obase + (size_t)(co0 + 2) * NPIX] = f2bf(a2);
  pc[obase + (size_t)(co0 + 3) * NPIX] = f2bf(a3);
}

// ---------- K6: clean MFMA pin GEMM (K=64 -> 256), transposed epilogue ----------
__global__ __launch_bounds__(256) void k6_pin(
    const unsigned short* __restrict__ pc, const unsigned short* __restrict__ y2,
    const unsigned short* __restrict__ pinb, unsigned short* __restrict__ ag) {
  __shared__ __align__(16) unsigned char bt[64 * 128];      // [px][64ci] swizzled
  __shared__ __align__(16) unsigned short epi[4][16][72];   // [wave][co16][px64+pad]
  int t = threadIdx.x, blk = blockIdx.x;
  int b = blk >> 8, hw0 = (blk & 255) * 64;
  int px = t & 63, cb = t >> 6;
  {
    const unsigned short* base = (cb == 0) ? (pc + (size_t)b * 16 * NPIX)
                                           : (y2 + (size_t)b * 64 * NPIX);
#pragma unroll
    for (int j = 0; j < 16; j += 2) {
      int ch = cb * 16 + j;
      unsigned short v0 = base[(size_t)ch * NPIX + hw0 + px];
      unsigned short v1 = base[(size_t)(ch + 1) * NPIX + hw0 + px];
      unsigned int addr = ((unsigned)(px * 128 + ch * 2)) ^ ((px & 7) << 4);
      *(unsigned int*)&bt[addr] = pack2(v0, v1);
    }
  }
  __syncthreads();
  int lane = t & 63, wv = t >> 6, l16 = lane & 15, g = lane >> 4;
  bf16x8 A[4][2];
#pragma unroll
  for (int ct = 0; ct < 4; ++ct) {
    int co = wv * 64 + ct * 16 + l16;
#pragma unroll
    for (int kh = 0; kh < 2; ++kh)
      A[ct][kh] = *(const bf16x8*)(pinb + (size_t)co * 64 + kh * 32 + g * 8);
  }
  f32x4 acc[4][4];
#pragma unroll
  for (int ct = 0; ct < 4; ++ct)
#pragma unroll
    for (int nt = 0; nt < 4; ++nt) acc[ct][nt] = (f32x4)0.f;
#pragma unroll
  for (int nt = 0; nt < 4; ++nt) {
    int pp = nt * 16 + l16;
#pragma unroll
    for (int kh = 0; kh < 2; ++kh) {
      unsigned int addr = ((unsigned)(pp * 128 + (kh * 32 + g * 8) * 2)) ^ ((pp & 7) << 4);
      bf16x8 Bf = *(const bf16x8*)&bt[addr];
#pragma unroll
      for (int ct = 0; ct < 4; ++ct) acc[ct][nt] = mfma16(A[ct][kh], Bf, acc[ct][nt]);
    }
  }
  // epilogue -> ag[b][row][co][w]
  int row6 = hw0 >> 7, wb6 = hw0 & 127;
  unsigned short* ab = ag + ((size_t)(b * 128 + row6) * 256) * 128 + wb6;
#pragma unroll
  for (int ct = 0; ct < 4; ++ct) {
#pragma unroll
    for (int nt = 0; nt < 4; ++nt)
#pragma unroll
      for (int r = 0; r < 4; ++r)
        epi[wv][g * 4 + r][nt * 16 + l16] = f2bf(acc[ct][nt][r]);
#pragma unroll
    for (int i = 0; i < 2; ++i) {
      int chunk = i * 64 + lane, co_l = chunk >> 3, oct = chunk & 7;
      u32x4 v = *(const u32x4*)&epi[wv][co_l][oct * 8];
      int co = wv * 64 + ct * 16 + co_l;
      *(u32x4*)(ab + (size_t)co * 128 + oct * 8) = v;
    }
  }
}

// ---------- K7: fused dw3x3 + gelu*gate + MFMA pout (K=128) + residual ----------
// Round-12 form (best measured: 40.6us): 256 thr, 64-px tile, erff, loads in loop.
__global__ __launch_bounds__(256) void k7_fdfn(
    const unsigned short* __restrict__ ag, const float* __restrict__ dww,
    const unsigned short* __restrict__ pob, const unsigned short* __restrict__ x1,
    float* __restrict__ out) {
  __shared__ __align__(16) unsigned char bt[64 * 256];   // [px64][128ch] bf16 swizzled
  __shared__ float dwl[1152];
  int t = threadIdx.x;
  int blk0 = blockIdx.x;
  int blk = (blk0 & 7) * 256 + (blk0 >> 3);              // 2048 = 8 * 256, bijective
  int b = blk >> 8, rr = blk & 255;
  int row = rr >> 1, w0t = (rr & 1) * 64;
  for (int i = t; i < 1152; i += 256) dwl[i] = dww[i];
  __syncthreads();
  // phase 1: h = gelu(dw(a)) * g, thread = (ch-pair, px-octet)
#pragma unroll 1
  for (int it = 0; it < 2; ++it) {
    int idx = it * 256 + t;
    int chp = idx >> 3, oct = idx & 7;
    int ch0 = chp * 2;
    int w0 = w0t + oct * 8;
    float rowa[2][3][10];
    float gt[2][8];
#pragma unroll
    for (int cc = 0; cc < 2; ++cc) {
      int ch = ch0 + cc;
#pragma unroll
      for (int dy = 0; dy < 3; ++dy) {
#pragma unroll
        for (int i2 = 0; i2 < 10; ++i2) rowa[cc][dy][i2] = 0.f;
        int hh = row + dy - 1;
        if ((unsigned)hh < 128u) {
          const unsigned short* rp = ag + ((size_t)(b * 128 + hh) * 256 + ch) * 128 + w0;
          unpack8(*(const u32x4*)rp, &rowa[cc][dy][1]);
          if (w0 > 0) rowa[cc][dy][0] = bf2f(rp[-1]);
          if (w0 < 120) rowa[cc][dy][9] = bf2f(rp[8]);
        }
      }
      unpack8(*(const u32x4*)(ag + ((size_t)(b * 128 + row) * 256 + 128 + ch) * 128 + w0), gt[cc]);
    }
    float wgt[2][9];
#pragma unroll
    for (int cc = 0; cc < 2; ++cc)
#pragma unroll
      for (int j = 0; j < 9; ++j) wgt[cc][j] = dwl[(ch0 + cc) * 9 + j];
#pragma unroll
    for (int i2 = 0; i2 < 8; ++i2) {
      unsigned short h2[2];
#pragma unroll
      for (int cc = 0; cc < 2; ++cc) {
        float a = 0.f;
#pragma unroll
        for (int dy = 0; dy < 3; ++dy)
#pragma unroll
          for (int dx = 0; dx < 3; ++dx)
            a = fmaf(wgt[cc][dy * 3 + dx], rowa[cc][dy][i2 + dx], a);
        float gl = 0.5f * a * (1.f + erff(a * 0.70710678118654752f)) * gt[cc][i2];
        h2[cc] = f2bf(gl);
      }
      int pxl = oct * 8 + i2;
      unsigned int f = (unsigned)(((pxl & 7) ^ (pxl >> 3)) << 4);
      unsigned int addr = (unsigned)(pxl * 256) + (((unsigned)(ch0 * 2)) ^ f);
      *(unsigned int*)&bt[addr] = pack2(h2[0], h2[1]);
    }
  }
  __syncthreads();
  // phase 2: MFMA pout: per wave 16 co x 64 px, K=128
  int lane = t & 63, wv = t >> 6, l16 = lane & 15, g = lane >> 4;
  bf16x8 A[4];
#pragma unroll
  for (int kh = 0; kh < 4; ++kh)
    A[kh] = *(const bf16x8*)(pob + (size_t)(wv * 16 + l16) * 128 + kh * 32 + g * 8);
  f32x4 acc[4];
#pragma unroll
  for (int nt = 0; nt < 4; ++nt) acc[nt] = (f32x4)0.f;
#pragma unroll
  for (int nt = 0; nt < 4; ++nt) {
    int pp = nt * 16 + l16;
    unsigned int f = (unsigned)(((pp & 7) ^ (pp >> 3)) << 4);
#pragma unroll
    for (int kh = 0; kh < 4; ++kh) {
      unsigned int addr = (unsigned)(pp * 256) + (((unsigned)((kh * 32 + g * 8) * 2)) ^ f);
      bf16x8 Bf = *(const bf16x8*)&bt[addr];
      acc[nt] = mfma16(A[kh], Bf, acc[nt]);
    }
  }
  __syncthreads();
  // epilogue: reuse bt as f32 [wave][16co][64px]; 16B coalesced stores + residual
  float* ebuf = (float*)&bt[wv * 4096];
#pragma unroll
  for (int nt = 0; nt < 4; ++nt)
#pragma unroll
    for (int r = 0; r < 4; ++r)
      ebuf[(g * 4 + r) * 64 + nt * 16 + l16] = acc[nt][r];
  const unsigned short* x1b = x1 + (size_t)b * 64 * NPIX + row * 128 + w0t;
  float* ob = out + (size_t)b * 64 * NPIX + row * 128 + w0t;
#pragma unroll
  for (int i = 0; i < 4; ++i) {
    int chunk = i * 64 + lane;
    int co_l = chunk >> 4, q4 = (chunk & 15) * 4;
    f32x4 v = *(const f32x4*)&ebuf[co_l * 64 + q4];
    int co = wv * 16 + co_l;
    uint2 xv = *(const uint2*)(x1b + (size_t)co * NPIX + q4);
    f32x4 o;
    o[0] = v[0] + bf2f((unsigned short)(xv.x & 0xffffu));
    o[1] = v[1] + bf2f((unsigned short)(xv.x >> 16));
    o[2] = v[2] + bf2f((unsigned short)(xv.y & 0xffffu));
    o[3] = v[3] + bf2f((unsigned short)(xv.y >> 16));
    *(f32x4*)(ob + (size_t)co * NPIX + q4) = o;
  }
}

// ---------- launch ----------
extern "C" void kernel_launch(void* const* d_in, const int* in_sizes, int n_in,
                              void* d_out, int out_size, void* d_ws, size_t ws_size,
                              hipStream_t stream) {
  const float* x       = (const float*)d_in[0];
  const float* ln1_w   = (const float*)d_in[1];
  const float* ln1_b   = (const float*)d_in[2];
  const float* qkv_w   = (const float*)d_in[3];
  const float* qkv_dww = (const float*)d_in[4];
  const float* temp    = (const float*)d_in[5];
  const float* mix     = (const float*)d_in[6];
  const float* proj_w  = (const float*)d_in[7];
  const float* ln2_w   = (const float*)d_in[8];
  const float* ln2_b   = (const float*)d_in[9];
  const float* pconv_w = (const float*)d_in[10];
  const float* pin_w   = (const float*)d_in[11];
  const float* dw_w    = (const float*)d_in[12];
  const float* pout_w  = (const float*)d_in[13];
  float* out = (float*)d_out;

  // Workspace (byte offsets):
  //   qkv  [0, 50331648)           k1->k2 (bf16, row-major)
  //   qkvd [50331648, 100663296)   k2->k4 (bf16, row-major)
  //   x1   [100663296, 117440512)  k4->k7 (bf16)
  //   weights @117440512
  //   parts @0, M @2MB, y2 @4MB, pc @20.97MB -- in dead qkv head
  //   ag   [33554432, 100663296)   k6->k7 (row-major; dead qkv tail + dead qkvd)
  if (ws_size < (size_t)117515776) return;
  char* w8 = (char*)d_ws;
  unsigned short* qkv  = (unsigned short*)(w8 + 0);
  unsigned short* qkvd = (unsigned short*)(w8 + 50331648);
  unsigned short* x1   = (unsigned short*)(w8 + 100663296);
  unsigned short* wq2  = (unsigned short*)(w8 + 117440512);
  float*          s1   = (float*)(w8 + 117465088);
  float*          s2   = (float*)(w8 + 117465856);
  unsigned short* pinb = (unsigned short*)(w8 + 117466624);
  unsigned short* pob  = (unsigned short*)(w8 + 117499392);
  float*          parts= (float*)(w8 + 0);
  unsigned short* M    = (unsigned short*)(w8 + 2097152);
  unsigned short* y2   = (unsigned short*)(w8 + 4194304);
  unsigned short* pc   = (unsigned short*)(w8 + 20971520);
  unsigned short* ag   = (unsigned short*)(w8 + 33554432);

  k0_prep<<<97, 256, 0, stream>>>(qkv_w, ln1_w, ln1_b, pin_w, pout_w, wq2, s1, s2, pinb, pob);
  k1_qkv<<<2048, 256, 0, stream>>>(x, wq2, s1, s2, qkv);
  k2_dw3x3<<<6144, 256, 0, stream>>>(qkv, qkv_dww, qkvd);
  k3a_mfma<<<512, 256, 0, stream>>>(qkvd, parts);
  k3bc<<<8, 256, 0, stream>>>(parts, temp, mix, proj_w, M);
  k4_av<<<2048, 256, 0, stream>>>(qkvd, M, x, ln2_w, ln2_b, x1, y2);
  k5_pconv<<<2048, 256, 0, stream>>>(y2, pconv_w, pc);
  k6_pin<<<2048, 256, 0, stream>>>(pc, y2, pinb, ag);
  k7_fdfn<<<2048, 256, 0, stream>>>(ag, dw_w, pob, x1, out);
}